// Round 12
// baseline (295.049 us; speedup 1.0000x reference)
//
#include <hip/hip_runtime.h>
#include <math.h>

static constexpr int N = 50000;
static constexpr int E = 800000;
static constexpr int D = 128;      // D_IN = D_HID
static constexpr int DO = 64;      // D_OUT
static constexpr int CAP = 64;     // ELL row capacity (Poisson(16); P(deg>64) ~ 1e-26)

// ---- bf16 helpers ----
__device__ __forceinline__ unsigned pack_bf16(float a, float b) {
  unsigned ua = __float_as_uint(a), ub = __float_as_uint(b);
  ua = (ua + 0x7FFFu + ((ua >> 16) & 1u)) >> 16;
  ub = (ub + 0x7FFFu + ((ub >> 16) & 1u)) >> 16;
  return ua | (ub << 16);
}
__device__ __forceinline__ float blo(unsigned u) { return __uint_as_float(u << 16); }
__device__ __forceinline__ float bhi(unsigned u) { return __uint_as_float(u & 0xFFFF0000u); }

// ---- non-temporal vector load/store helpers (ext_vector types for the builtin) ----
typedef int v4i __attribute__((ext_vector_type(4)));
typedef int v2i __attribute__((ext_vector_type(2)));
typedef float v2f __attribute__((ext_vector_type(2)));

__device__ __forceinline__ int4 nt_load4(const int2* p) {
  v4i v = __builtin_nontemporal_load((const v4i*)p);
  return make_int4(v.x, v.y, v.z, v.w);
}
__device__ __forceinline__ int2 nt_load2(const int2* p) {
  v2i v = __builtin_nontemporal_load((const v2i*)p);
  return make_int2(v.x, v.y);
}
__device__ __forceinline__ void nt_store2(int2* p, int a, int b) {
  v2i v; v.x = a; v.y = b;
  __builtin_nontemporal_store(v, (v2i*)p);
}

// ---------------- zero per-dst counters ----------------
__global__ __launch_bounds__(256) void k_zero(int* __restrict__ cnt) {
  int i = blockIdx.x * 256 + threadIdx.x;
  if (i < N) cnt[i] = 0;
}

// ---------------- single-pass ELL build: slot = atomic count, row = dst*CAP ----------------
__global__ __launch_bounds__(256) void k_build_ell(const int* __restrict__ src,
                                                   const int* __restrict__ dst,
                                                   const float* __restrict__ ew,
                                                   int* __restrict__ cnt,
                                                   int2* __restrict__ ell) {
  int e = blockIdx.x * 256 + threadIdx.x;
  if (e >= E) return;
  int s = __builtin_nontemporal_load(src + e);
  int d = __builtin_nontemporal_load(dst + e);
  float w = __builtin_nontemporal_load(ew + e);
  int pos = __hip_atomic_fetch_add(&cnt[d], 1, __ATOMIC_RELAXED, __HIP_MEMORY_SCOPE_AGENT);
  if (pos < CAP)   // statistically unreachable; guards memory safety
    nt_store2(&ell[(size_t)d * CAP + pos], s, __float_as_int(w));
}

// ---------------- deg -> dinv -> cast x to scaled bf16, one wave/node ----------------
__global__ __launch_bounds__(256) void k_degcast(const float* __restrict__ x,
                                                 const int* __restrict__ cnt,
                                                 const int2* __restrict__ ell,
                                                 float* __restrict__ dinv,
                                                 unsigned* __restrict__ bhs) {
  int node = blockIdx.x * 4 + (threadIdx.x >> 6);
  if (node >= N) return;
  int lane = threadIdx.x & 63;

  int len = cnt[node];
  float sum = 0.f;
  if (lane < len) {
    int2 pe = nt_load2(&ell[(size_t)node * CAP + lane]);
    sum = __int_as_float(pe.y);
  }
#pragma unroll
  for (int off = 1; off < 64; off <<= 1) sum += __shfl_xor(sum, off, 64);

  float dv = 1.0f / sqrtf(1.0f + sum);
  if (lane == 0) dinv[node] = dv;

  v2f v = __builtin_nontemporal_load((const v2f*)x + (size_t)node * 64 + lane);
  bhs[(size_t)node * 64 + lane] = pack_bf16(v.x * dv, v.y * dv);
}

// ---------------- aggregation core (bf16 scaled gather, fp32 accumulate) ----------------
// returns dinv[node] * ( bhs[node] + sum_e ew_e * bhs[src_e] )  per lane (2 dims)
// ELL rows are 512B-aligned; edge data is single-use -> non-temporal loads.
__device__ __forceinline__ float2 agg_core(const unsigned* __restrict__ bp,
                                           const int2* __restrict__ ell,
                                           int node, int len, float s) {
  unsigned hb = bp[(size_t)node * 64];
  float ax = blo(hb), ay = bhi(hb);

  const int2* row = ell + (size_t)node * CAP;
  int e = 0;
  for (; e + 8 <= len; e += 8) {
    int4 p0 = nt_load4(row + e + 0);
    int4 p1 = nt_load4(row + e + 2);
    int4 p2 = nt_load4(row + e + 4);
    int4 p3 = nt_load4(row + e + 6);
    unsigned b0 = bp[(size_t)p0.x * 64];
    unsigned b1 = bp[(size_t)p0.z * 64];
    unsigned b2 = bp[(size_t)p1.x * 64];
    unsigned b3 = bp[(size_t)p1.z * 64];
    unsigned b4 = bp[(size_t)p2.x * 64];
    unsigned b5 = bp[(size_t)p2.z * 64];
    unsigned b6 = bp[(size_t)p3.x * 64];
    unsigned b7 = bp[(size_t)p3.z * 64];
    float w0 = __int_as_float(p0.y), w1 = __int_as_float(p0.w);
    float w2 = __int_as_float(p1.y), w3 = __int_as_float(p1.w);
    float w4 = __int_as_float(p2.y), w5 = __int_as_float(p2.w);
    float w6 = __int_as_float(p3.y), w7 = __int_as_float(p3.w);
    ax = fmaf(blo(b0), w0, ax); ay = fmaf(bhi(b0), w0, ay);
    ax = fmaf(blo(b1), w1, ax); ay = fmaf(bhi(b1), w1, ay);
    ax = fmaf(blo(b2), w2, ax); ay = fmaf(bhi(b2), w2, ay);
    ax = fmaf(blo(b3), w3, ax); ay = fmaf(bhi(b3), w3, ay);
    ax = fmaf(blo(b4), w4, ax); ay = fmaf(bhi(b4), w4, ay);
    ax = fmaf(blo(b5), w5, ax); ay = fmaf(bhi(b5), w5, ay);
    ax = fmaf(blo(b6), w6, ax); ay = fmaf(bhi(b6), w6, ay);
    ax = fmaf(blo(b7), w7, ax); ay = fmaf(bhi(b7), w7, ay);
  }
  for (; e + 2 <= len; e += 2) {
    int4 p0 = nt_load4(row + e);
    unsigned b0 = bp[(size_t)p0.x * 64];
    unsigned b1 = bp[(size_t)p0.z * 64];
    float w0 = __int_as_float(p0.y), w1 = __int_as_float(p0.w);
    ax = fmaf(blo(b0), w0, ax); ay = fmaf(bhi(b0), w0, ay);
    ax = fmaf(blo(b1), w1, ax); ay = fmaf(bhi(b1), w1, ay);
  }
  if (e < len) {
    int2 pe = nt_load2(row + e);
    float w = __int_as_float(pe.y);
    unsigned b = bp[(size_t)pe.x * 64];
    ax = fmaf(blo(b), w, ax); ay = fmaf(bhi(b), w, ay);
  }
  float2 r; r.x = ax * s; r.y = ay * s;
  return r;
}

// all layers: bf16 output (GEMM A-operand)
__global__ __launch_bounds__(256) void k_agg_bf16(const unsigned* __restrict__ bhs,
                                                  const int* __restrict__ cnt,
                                                  const int2* __restrict__ ell,
                                                  const float* __restrict__ dinv,
                                                  unsigned* __restrict__ outb) {
  int node = blockIdx.x * 4 + (threadIdx.x >> 6);
  if (node >= N) return;
  int lane = threadIdx.x & 63;
  float2 r = agg_core(bhs + lane, ell, node, cnt[node], dinv[node]);
  outb[(size_t)node * 64 + lane] = pack_bf16(r.x, r.y);
}

// ---------------- GEMM: bhs_next = bf16( relu(A@W + b) * dinv )  (A packed bf16) ----------------
__global__ __launch_bounds__(256) void k_gemm_relu_bf16(const unsigned* __restrict__ Ab,
                                                        const float* __restrict__ W,
                                                        const float* __restrict__ bias,
                                                        const float* __restrict__ dinv,
                                                        unsigned* __restrict__ outb) {
  __shared__ __align__(16) float Wl[128][128];
  __shared__ __align__(16) float Al[32][128];
  const int tid = threadIdx.x;

  {
    const float4* W4 = (const float4*)W;
    float4* Wl4 = (float4*)&Wl[0][0];
#pragma unroll
    for (int i = 0; i < 16; ++i) Wl4[tid + i * 256] = W4[tid + i * 256];
  }
  const int row0 = blockIdx.x * 32;
  {  // A tile: 32 rows x 64 uints = 512 uint4, unpack bf16 -> fp32 LDS
#pragma unroll
    for (int i = 0; i < 2; ++i) {
      int idx = tid + i * 256;
      int r = idx >> 4, c4 = idx & 15;
      uint4 v = make_uint4(0u, 0u, 0u, 0u);
      if (row0 + r < N) v = *(const uint4*)&Ab[(size_t)(row0 + r) * 64 + c4 * 4];
      float* dp = &Al[r][c4 * 8];
      dp[0] = blo(v.x); dp[1] = bhi(v.x);
      dp[2] = blo(v.y); dp[3] = bhi(v.y);
      dp[4] = blo(v.z); dp[5] = bhi(v.z);
      dp[6] = blo(v.w); dp[7] = bhi(v.w);
    }
  }
  __syncthreads();

  const int c0 = (tid & 31) * 4;
  const int r0 = (tid >> 5) * 4;
  float acc[4][4] = {};
  for (int k4 = 0; k4 < 32; ++k4) {
    float4 a[4];
#pragma unroll
    for (int r = 0; r < 4; ++r) a[r] = *(const float4*)&Al[r0 + r][k4 * 4];
    float4 w[4];
#pragma unroll
    for (int kk = 0; kk < 4; ++kk) w[kk] = *(const float4*)&Wl[k4 * 4 + kk][c0];
#pragma unroll
    for (int r = 0; r < 4; ++r) {
      float av0 = a[r].x, av1 = a[r].y, av2 = a[r].z, av3 = a[r].w;
#pragma unroll
      for (int cc = 0; cc < 4; ++cc) {
        float wv0 = (&w[0].x)[cc], wv1 = (&w[1].x)[cc], wv2 = (&w[2].x)[cc], wv3 = (&w[3].x)[cc];
        float v = acc[r][cc];
        v = fmaf(av0, wv0, v);
        v = fmaf(av1, wv1, v);
        v = fmaf(av2, wv2, v);
        v = fmaf(av3, wv3, v);
        acc[r][cc] = v;
      }
    }
  }
  float4 b = *(const float4*)&bias[c0];
#pragma unroll
  for (int r = 0; r < 4; ++r) {
    int row = row0 + r0 + r;
    if (row < N) {
      float dv = dinv[row];
      float v0 = fmaxf(acc[r][0] + b.x, 0.f) * dv;
      float v1 = fmaxf(acc[r][1] + b.y, 0.f) * dv;
      float v2 = fmaxf(acc[r][2] + b.z, 0.f) * dv;
      float v3 = fmaxf(acc[r][3] + b.w, 0.f) * dv;
      uint2 u;
      u.x = pack_bf16(v0, v1);
      u.y = pack_bf16(v2, v3);
      *(uint2*)&outb[(size_t)row * 64 + (c0 >> 1)] = u;
    }
  }
}

// heads: A packed bf16; cols 0-63 -> mu, cols 64-127 -> std (fp32 out)
__global__ __launch_bounds__(256) void k_gemm_dual_bf16(const unsigned* __restrict__ Ab,
                                                        const float* __restrict__ Wmu,
                                                        const float* __restrict__ Wstd,
                                                        const float* __restrict__ bmu,
                                                        const float* __restrict__ bstd,
                                                        float* __restrict__ out) {
  __shared__ __align__(16) float Wl[128][128];
  __shared__ __align__(16) float Al[32][128];
  const int tid = threadIdx.x;

  {
    const float4* Wm4 = (const float4*)Wmu;
    const float4* Ws4 = (const float4*)Wstd;
#pragma unroll
    for (int i = 0; i < 8; ++i) {
      int idx = tid + i * 256;
      int k = idx >> 4;
      int c4 = idx & 15;
      *(float4*)&Wl[k][c4 * 4] = Wm4[idx];
      *(float4*)&Wl[k][64 + c4 * 4] = Ws4[idx];
    }
  }
  const int row0 = blockIdx.x * 32;
  {  // A tile: unpack bf16 -> fp32 LDS
#pragma unroll
    for (int i = 0; i < 2; ++i) {
      int idx = tid + i * 256;
      int r = idx >> 4, c4 = idx & 15;
      uint4 v = make_uint4(0u, 0u, 0u, 0u);
      if (row0 + r < N) v = *(const uint4*)&Ab[(size_t)(row0 + r) * 64 + c4 * 4];
      float* dp = &Al[r][c4 * 8];
      dp[0] = blo(v.x); dp[1] = bhi(v.x);
      dp[2] = blo(v.y); dp[3] = bhi(v.y);
      dp[4] = blo(v.z); dp[5] = bhi(v.z);
      dp[6] = blo(v.w); dp[7] = bhi(v.w);
    }
  }
  __syncthreads();

  const int c0 = (tid & 31) * 4;
  const int r0 = (tid >> 5) * 4;
  float acc[4][4] = {};
  for (int k4 = 0; k4 < 32; ++k4) {
    float4 a[4];
#pragma unroll
    for (int r = 0; r < 4; ++r) a[r] = *(const float4*)&Al[r0 + r][k4 * 4];
    float4 w[4];
#pragma unroll
    for (int kk = 0; kk < 4; ++kk) w[kk] = *(const float4*)&Wl[k4 * 4 + kk][c0];
#pragma unroll
    for (int r = 0; r < 4; ++r) {
      float av0 = a[r].x, av1 = a[r].y, av2 = a[r].z, av3 = a[r].w;
#pragma unroll
      for (int cc = 0; cc < 4; ++cc) {
        float wv0 = (&w[0].x)[cc], wv1 = (&w[1].x)[cc], wv2 = (&w[2].x)[cc], wv3 = (&w[3].x)[cc];
        float v = acc[r][cc];
        v = fmaf(av0, wv0, v);
        v = fmaf(av1, wv1, v);
        v = fmaf(av2, wv2, v);
        v = fmaf(av3, wv3, v);
        acc[r][cc] = v;
      }
    }
  }
  const bool is_mu = (c0 < DO);
  const int cc0 = is_mu ? c0 : (c0 - DO);
  const float* bsel = is_mu ? bmu : bstd;
  float4 b = *(const float4*)&bsel[cc0];
  float* base = is_mu ? out : (out + (size_t)N * DO);
#pragma unroll
  for (int r = 0; r < 4; ++r) {
    int row = row0 + r0 + r;
    if (row < N) {
      float4 v;
      v.x = acc[r][0] + b.x; v.y = acc[r][1] + b.y;
      v.z = acc[r][2] + b.z; v.w = acc[r][3] + b.w;
      *(float4*)&base[(size_t)row * DO + cc0] = v;
    }
  }
}

// ---------------- launcher ----------------

static inline char* align256(char* p) {
  return (char*)(((uintptr_t)p + 255) & ~(uintptr_t)255);
}

extern "C" void kernel_launch(void* const* d_in, const int* in_sizes, int n_in,
                              void* d_out, int out_size, void* d_ws, size_t ws_size,
                              hipStream_t stream) {
  const float* x    = (const float*)d_in[0];
  const int*   ei   = (const int*)d_in[1];     // [2, E] int32
  const float* ew   = (const float*)d_in[2];
  const float* W1   = (const float*)d_in[3];
  const float* b1   = (const float*)d_in[4];
  const float* W2   = (const float*)d_in[5];
  const float* b2   = (const float*)d_in[6];
  const float* Wmu  = (const float*)d_in[7];
  const float* bmu  = (const float*)d_in[8];
  const float* Wstd = (const float*)d_in[9];
  const float* bstd = (const float*)d_in[10];
  float* out = (float*)d_out;

  const int* srcI = ei;
  const int* dstI = ei + E;

  char* p = (char*)d_ws;
  float*    dinv = (float*)p;     p = align256(p + (size_t)N * 4);
  int*      cnt  = (int*)p;       p = align256(p + (size_t)N * 4);
  int2*     ell  = (int2*)p;      p = align256(p + (size_t)N * CAP * 8);  // 25.6 MB
  unsigned* bhs  = (unsigned*)p;  p = align256(p + (size_t)N * 64 * 4);   // 12.8 MB
  unsigned* bfA  = (unsigned*)p;  p = align256(p + (size_t)N * 64 * 4);   // 12.8 MB

  dim3 blk(256);
  const int gN    = (N + 255) / 256;
  const int gE    = (E + 255) / 256;
  const int gAgg  = (N + 3) / 4;
  const int gGemm = (N + 31) / 32;

  // graph precompute: zero -> single-pass ELL build -> deg/dinv/cast
  k_zero<<<gN, blk, 0, stream>>>(cnt);
  k_build_ell<<<gE, blk, 0, stream>>>(srcI, dstI, ew, cnt, ell);
  k_degcast<<<gAgg, blk, 0, stream>>>(x, cnt, ell, dinv, bhs);

  // layer 1: h1 = relu(A(x) @ W1 + b1)
  k_agg_bf16<<<gAgg, blk, 0, stream>>>(bhs, cnt, ell, dinv, bfA);
  k_gemm_relu_bf16<<<gGemm, blk, 0, stream>>>(bfA, W1, b1, dinv, bhs);

  // layer 2: h2 = relu(A(h1) @ W2 + b2)
  k_agg_bf16<<<gAgg, blk, 0, stream>>>(bhs, cnt, ell, dinv, bfA);
  k_gemm_relu_bf16<<<gGemm, blk, 0, stream>>>(bfA, W2, b2, dinv, bhs);

  // heads: one shared aggregation (bf16 out), dual projection
  k_agg_bf16<<<gAgg, blk, 0, stream>>>(bhs, cnt, ell, dinv, bfA);
  k_gemm_dual_bf16<<<gGemm, blk, 0, stream>>>(bfA, Wmu, Wstd, bmu, bstd, out);
}

// Round 13
// 231.998 us; speedup vs baseline: 1.2718x; 1.2718x over previous
//
#include <hip/hip_runtime.h>
#include <math.h>

static constexpr int N = 50000;
static constexpr int E = 800000;
static constexpr int D = 128;      // D_IN = D_HID
static constexpr int DO = 64;      // D_OUT
static constexpr int CAP = 64;     // ELL row capacity (Poisson(16); P(deg>64) ~ 1e-26)

// ---- bf16 helpers ----
__device__ __forceinline__ unsigned pack_bf16(float a, float b) {
  unsigned ua = __float_as_uint(a), ub = __float_as_uint(b);
  ua = (ua + 0x7FFFu + ((ua >> 16) & 1u)) >> 16;
  ub = (ub + 0x7FFFu + ((ub >> 16) & 1u)) >> 16;
  return ua | (ub << 16);
}
__device__ __forceinline__ float blo(unsigned u) { return __uint_as_float(u << 16); }
__device__ __forceinline__ float bhi(unsigned u) { return __uint_as_float(u & 0xFFFF0000u); }

typedef __attribute__((ext_vector_type(8))) short bf16x8;
typedef __attribute__((ext_vector_type(4))) float f32x4;

// ---------------- zero per-dst counters ----------------
__global__ __launch_bounds__(256) void k_zero(int* __restrict__ cnt) {
  int i = blockIdx.x * 256 + threadIdx.x;
  if (i < N) cnt[i] = 0;
}

// ---------------- single-pass ELL build: slot = atomic count, row = dst*CAP ----------------
__global__ __launch_bounds__(256) void k_build_ell(const int* __restrict__ src,
                                                   const int* __restrict__ dst,
                                                   const float* __restrict__ ew,
                                                   int* __restrict__ cnt,
                                                   int2* __restrict__ ell) {
  int e = blockIdx.x * 256 + threadIdx.x;
  if (e >= E) return;
  int s = src[e], d = dst[e];
  int pos = __hip_atomic_fetch_add(&cnt[d], 1, __ATOMIC_RELAXED, __HIP_MEMORY_SCOPE_AGENT);
  if (pos < CAP)   // statistically unreachable; guards memory safety
    ell[(size_t)d * CAP + pos] = make_int2(s, __float_as_int(ew[e]));
}

// ---------------- deg -> dinv -> cast x to scaled bf16, one wave/node ----------------
__global__ __launch_bounds__(256) void k_degcast(const float* __restrict__ x,
                                                 const int* __restrict__ cnt,
                                                 const int2* __restrict__ ell,
                                                 float* __restrict__ dinv,
                                                 unsigned* __restrict__ bhs) {
  int node = blockIdx.x * 4 + (threadIdx.x >> 6);
  if (node >= N) return;
  int lane = threadIdx.x & 63;

  int len = cnt[node];
  float sum = (lane < len) ? __int_as_float(ell[(size_t)node * CAP + lane].y) : 0.f;
#pragma unroll
  for (int off = 1; off < 64; off <<= 1) sum += __shfl_xor(sum, off, 64);

  float dv = 1.0f / sqrtf(1.0f + sum);
  if (lane == 0) dinv[node] = dv;

  float2 v = ((const float2*)x)[(size_t)node * 64 + lane];
  bhs[(size_t)node * 64 + lane] = pack_bf16(v.x * dv, v.y * dv);
}

// ---------------- aggregation core (bf16 scaled gather, fp32 accumulate) ----------------
__device__ __forceinline__ float2 agg_core(const unsigned* __restrict__ bp,
                                           const int2* __restrict__ ell,
                                           int node, int len, float s) {
  unsigned hb = bp[(size_t)node * 64];
  float ax = blo(hb), ay = bhi(hb);

  const int2* row = ell + (size_t)node * CAP;
  int e = 0;
  for (; e + 8 <= len; e += 8) {
    int4 p0 = *(const int4*)(row + e + 0);
    int4 p1 = *(const int4*)(row + e + 2);
    int4 p2 = *(const int4*)(row + e + 4);
    int4 p3 = *(const int4*)(row + e + 6);
    unsigned b0 = bp[(size_t)p0.x * 64];
    unsigned b1 = bp[(size_t)p0.z * 64];
    unsigned b2 = bp[(size_t)p1.x * 64];
    unsigned b3 = bp[(size_t)p1.z * 64];
    unsigned b4 = bp[(size_t)p2.x * 64];
    unsigned b5 = bp[(size_t)p2.z * 64];
    unsigned b6 = bp[(size_t)p3.x * 64];
    unsigned b7 = bp[(size_t)p3.z * 64];
    float w0 = __int_as_float(p0.y), w1 = __int_as_float(p0.w);
    float w2 = __int_as_float(p1.y), w3 = __int_as_float(p1.w);
    float w4 = __int_as_float(p2.y), w5 = __int_as_float(p2.w);
    float w6 = __int_as_float(p3.y), w7 = __int_as_float(p3.w);
    ax = fmaf(blo(b0), w0, ax); ay = fmaf(bhi(b0), w0, ay);
    ax = fmaf(blo(b1), w1, ax); ay = fmaf(bhi(b1), w1, ay);
    ax = fmaf(blo(b2), w2, ax); ay = fmaf(bhi(b2), w2, ay);
    ax = fmaf(blo(b3), w3, ax); ay = fmaf(bhi(b3), w3, ay);
    ax = fmaf(blo(b4), w4, ax); ay = fmaf(bhi(b4), w4, ay);
    ax = fmaf(blo(b5), w5, ax); ay = fmaf(bhi(b5), w5, ay);
    ax = fmaf(blo(b6), w6, ax); ay = fmaf(bhi(b6), w6, ay);
    ax = fmaf(blo(b7), w7, ax); ay = fmaf(bhi(b7), w7, ay);
  }
  for (; e + 2 <= len; e += 2) {
    int4 p0 = *(const int4*)(row + e);
    unsigned b0 = bp[(size_t)p0.x * 64];
    unsigned b1 = bp[(size_t)p0.z * 64];
    float w0 = __int_as_float(p0.y), w1 = __int_as_float(p0.w);
    ax = fmaf(blo(b0), w0, ax); ay = fmaf(bhi(b0), w0, ay);
    ax = fmaf(blo(b1), w1, ax); ay = fmaf(bhi(b1), w1, ay);
  }
  if (e < len) {
    int2 pe = row[e];
    float w = __int_as_float(pe.y);
    unsigned b = bp[(size_t)pe.x * 64];
    ax = fmaf(blo(b), w, ax); ay = fmaf(bhi(b), w, ay);
  }
  float2 r; r.x = ax * s; r.y = ay * s;
  return r;
}

// all layers: bf16 output (GEMM A-operand)
__global__ __launch_bounds__(256) void k_agg_bf16(const unsigned* __restrict__ bhs,
                                                  const int* __restrict__ cnt,
                                                  const int2* __restrict__ ell,
                                                  const float* __restrict__ dinv,
                                                  unsigned* __restrict__ outb) {
  int node = blockIdx.x * 4 + (threadIdx.x >> 6);
  if (node >= N) return;
  int lane = threadIdx.x & 63;
  float2 r = agg_core(bhs + lane, ell, node, cnt[node], dinv[node]);
  outb[(size_t)node * 64 + lane] = pack_bf16(r.x, r.y);
}

// ---------------- MFMA GEMM: bhs_next = bf16( relu(A@W + b) * dinv ) ----------------
// block: 64 rows x 128 cols, 4 waves; wave w owns rows [16w,16w+16)
// A packed bf16 [N][64 uint]; W fp32 [128][128] cast+transposed to LDS bf16 Wt[col][k]
__global__ __launch_bounds__(256) void k_gemm_relu_mfma(const unsigned* __restrict__ Ab,
                                                        const float* __restrict__ W,
                                                        const float* __restrict__ bias,
                                                        const float* __restrict__ dinv,
                                                        unsigned* __restrict__ outb) {
  __shared__ __align__(16) unsigned Al[64][68];   // 64 rows x 64 uints (+4 pad)
  __shared__ __align__(16) unsigned Wt[128][72];  // 128 cols x 64 uints (+8 pad), bf16x2
  const int tid = threadIdx.x;
  const int row0 = blockIdx.x * 64;

  {  // stage A: 1024 uint4
#pragma unroll
    for (int i = 0; i < 4; ++i) {
      int idx = tid + i * 256;
      int r = idx >> 4, c4 = idx & 15;
      uint4 v = make_uint4(0u, 0u, 0u, 0u);
      if (row0 + r < N) v = *(const uint4*)&Ab[(size_t)(row0 + r) * 64 + c4 * 4];
      *(uint4*)&Al[r][c4 * 4] = v;
    }
  }
  {  // stage W transposed, cast to bf16: Wt[col][k2] = (W[2k2][col], W[2k2+1][col])
    int col = tid & 127, half = tid >> 7;
#pragma unroll
    for (int m = 0; m < 32; ++m) {
      int k2 = half * 32 + m;
      float w0 = W[(size_t)(2 * k2) * 128 + col];
      float w1 = W[(size_t)(2 * k2 + 1) * 128 + col];
      Wt[col][k2] = pack_bf16(w0, w1);
    }
  }
  __syncthreads();

  const int w = tid >> 6, l = tid & 63, c = l & 15, q = l >> 4;
  f32x4 acc[8] = {};
#pragma unroll
  for (int ks = 0; ks < 4; ++ks) {
    bf16x8 af = *(const bf16x8*)&Al[16 * w + c][ks * 16 + 4 * q];
#pragma unroll
    for (int ct = 0; ct < 8; ++ct) {
      bf16x8 bf = *(const bf16x8*)&Wt[ct * 16 + c][ks * 16 + 4 * q];
      acc[ct] = __builtin_amdgcn_mfma_f32_16x16x32_bf16(af, bf, acc[ct], 0, 0, 0);
    }
  }
  // epilogue: C/D layout col=lane&15, row=(lane>>4)*4+reg
#pragma unroll
  for (int ct = 0; ct < 8; ++ct) {
    int col = ct * 16 + c;
    float bb = bias[col];
#pragma unroll
    for (int j = 0; j < 4; ++j) {
      int row = row0 + 16 * w + 4 * q + j;
      float v = 0.f;
      if (row < N) v = fmaxf(acc[ct][j] + bb, 0.f) * dinv[row];
      float o = __shfl_xor(v, 1);
      if (((c & 1) == 0) && row < N)
        outb[(size_t)row * 64 + (col >> 1)] = pack_bf16(v, o);
    }
  }
}

// heads: A packed bf16; Wt = [Wmu | Wstd] -> mu (cols 0-63), std (cols 64-127), fp32 out
__global__ __launch_bounds__(256) void k_gemm_dual_mfma(const unsigned* __restrict__ Ab,
                                                        const float* __restrict__ Wmu,
                                                        const float* __restrict__ Wstd,
                                                        const float* __restrict__ bmu,
                                                        const float* __restrict__ bstd,
                                                        float* __restrict__ out) {
  __shared__ __align__(16) unsigned Al[64][68];
  __shared__ __align__(16) unsigned Wt[128][72];
  const int tid = threadIdx.x;
  const int row0 = blockIdx.x * 64;

  {
#pragma unroll
    for (int i = 0; i < 4; ++i) {
      int idx = tid + i * 256;
      int r = idx >> 4, c4 = idx & 15;
      uint4 v = make_uint4(0u, 0u, 0u, 0u);
      if (row0 + r < N) v = *(const uint4*)&Ab[(size_t)(row0 + r) * 64 + c4 * 4];
      *(uint4*)&Al[r][c4 * 4] = v;
    }
  }
  {
    int col = tid & 127, half = tid >> 7;
    const float* base = (col < DO) ? Wmu : Wstd;
    int cc = (col < DO) ? col : (col - DO);
#pragma unroll
    for (int m = 0; m < 32; ++m) {
      int k2 = half * 32 + m;
      float w0 = base[(size_t)(2 * k2) * DO + cc];
      float w1 = base[(size_t)(2 * k2 + 1) * DO + cc];
      Wt[col][k2] = pack_bf16(w0, w1);
    }
  }
  __syncthreads();

  const int w = tid >> 6, l = tid & 63, c = l & 15, q = l >> 4;
  f32x4 acc[8] = {};
#pragma unroll
  for (int ks = 0; ks < 4; ++ks) {
    bf16x8 af = *(const bf16x8*)&Al[16 * w + c][ks * 16 + 4 * q];
#pragma unroll
    for (int ct = 0; ct < 8; ++ct) {
      bf16x8 bf = *(const bf16x8*)&Wt[ct * 16 + c][ks * 16 + 4 * q];
      acc[ct] = __builtin_amdgcn_mfma_f32_16x16x32_bf16(af, bf, acc[ct], 0, 0, 0);
    }
  }
#pragma unroll
  for (int ct = 0; ct < 8; ++ct) {
    int col = ct * 16 + c;
    const bool is_mu = (col < DO);
    float bb = is_mu ? bmu[col] : bstd[col - DO];
    float* base = is_mu ? out : (out + (size_t)N * DO);
    int cc = is_mu ? col : (col - DO);
#pragma unroll
    for (int j = 0; j < 4; ++j) {
      int row = row0 + 16 * w + 4 * q + j;
      if (row < N) base[(size_t)row * DO + cc] = acc[ct][j] + bb;
    }
  }
}

// ---------------- launcher ----------------

static inline char* align256(char* p) {
  return (char*)(((uintptr_t)p + 255) & ~(uintptr_t)255);
}

extern "C" void kernel_launch(void* const* d_in, const int* in_sizes, int n_in,
                              void* d_out, int out_size, void* d_ws, size_t ws_size,
                              hipStream_t stream) {
  const float* x    = (const float*)d_in[0];
  const int*   ei   = (const int*)d_in[1];     // [2, E] int32
  const float* ew   = (const float*)d_in[2];
  const float* W1   = (const float*)d_in[3];
  const float* b1   = (const float*)d_in[4];
  const float* W2   = (const float*)d_in[5];
  const float* b2   = (const float*)d_in[6];
  const float* Wmu  = (const float*)d_in[7];
  const float* bmu  = (const float*)d_in[8];
  const float* Wstd = (const float*)d_in[9];
  const float* bstd = (const float*)d_in[10];
  float* out = (float*)d_out;

  const int* srcI = ei;
  const int* dstI = ei + E;

  char* p = (char*)d_ws;
  float*    dinv = (float*)p;     p = align256(p + (size_t)N * 4);
  int*      cnt  = (int*)p;       p = align256(p + (size_t)N * 4);
  int2*     ell  = (int2*)p;      p = align256(p + (size_t)N * CAP * 8);  // 25.6 MB
  unsigned* bhs  = (unsigned*)p;  p = align256(p + (size_t)N * 64 * 4);   // 12.8 MB
  unsigned* bfA  = (unsigned*)p;  p = align256(p + (size_t)N * 64 * 4);   // 12.8 MB

  dim3 blk(256);
  const int gN    = (N + 255) / 256;
  const int gE    = (E + 255) / 256;
  const int gAgg  = (N + 3) / 4;
  const int gGemm = (N + 63) / 64;   // 782

  // graph precompute: zero -> single-pass ELL build -> deg/dinv/cast
  k_zero<<<gN, blk, 0, stream>>>(cnt);
  k_build_ell<<<gE, blk, 0, stream>>>(srcI, dstI, ew, cnt, ell);
  k_degcast<<<gAgg, blk, 0, stream>>>(x, cnt, ell, dinv, bhs);

  // layer 1: h1 = relu(A(x) @ W1 + b1)
  k_agg_bf16<<<gAgg, blk, 0, stream>>>(bhs, cnt, ell, dinv, bfA);
  k_gemm_relu_mfma<<<gGemm, blk, 0, stream>>>(bfA, W1, b1, dinv, bhs);

  // layer 2: h2 = relu(A(h1) @ W2 + b2)
  k_agg_bf16<<<gAgg, blk, 0, stream>>>(bhs, cnt, ell, dinv, bfA);
  k_gemm_relu_mfma<<<gGemm, blk, 0, stream>>>(bfA, W2, b2, dinv, bhs);

  // heads: one shared aggregation (bf16 out), dual projection
  k_agg_bf16<<<gAgg, blk, 0, stream>>>(bhs, cnt, ell, dinv, bfA);
  k_gemm_dual_mfma<<<gGemm, blk, 0, stream>>>(bfA, Wmu, Wstd, bmu, bstd, out);
}

// Round 14
// 200.842 us; speedup vs baseline: 1.4691x; 1.1551x over previous
//
#include <hip/hip_runtime.h>
#include <math.h>

static constexpr int N = 50000;
static constexpr int E = 800000;
static constexpr int D = 128;      // D_IN = D_HID
static constexpr int DO = 64;      // D_OUT
static constexpr int CAP = 64;     // ELL row capacity (Poisson(16); P(deg>64) ~ 1e-26)

// ---- bf16 helpers ----
__device__ __forceinline__ unsigned pack_bf16(float a, float b) {
  unsigned ua = __float_as_uint(a), ub = __float_as_uint(b);
  ua = (ua + 0x7FFFu + ((ua >> 16) & 1u)) >> 16;
  ub = (ub + 0x7FFFu + ((ub >> 16) & 1u)) >> 16;
  return ua | (ub << 16);
}
__device__ __forceinline__ float blo(unsigned u) { return __uint_as_float(u << 16); }
__device__ __forceinline__ float bhi(unsigned u) { return __uint_as_float(u & 0xFFFF0000u); }

typedef __attribute__((ext_vector_type(8))) short bf16x8;
typedef __attribute__((ext_vector_type(4))) float f32x4;

// ---------------- zero per-dst counters ----------------
__global__ __launch_bounds__(256) void k_zero(int* __restrict__ cnt) {
  int i = blockIdx.x * 256 + threadIdx.x;
  if (i < N) cnt[i] = 0;
}

// ---------------- single-pass ELL build: slot = atomic count, row = dst*CAP ----------------
__global__ __launch_bounds__(256) void k_build_ell(const int* __restrict__ src,
                                                   const int* __restrict__ dst,
                                                   const float* __restrict__ ew,
                                                   int* __restrict__ cnt,
                                                   int2* __restrict__ ell) {
  int e = blockIdx.x * 256 + threadIdx.x;
  if (e >= E) return;
  int s = src[e], d = dst[e];
  int pos = __hip_atomic_fetch_add(&cnt[d], 1, __ATOMIC_RELAXED, __HIP_MEMORY_SCOPE_AGENT);
  if (pos < CAP)   // statistically unreachable; guards memory safety
    ell[(size_t)d * CAP + pos] = make_int2(s, __float_as_int(ew[e]));
}

// ---------------- deg -> dinv -> cast x to scaled bf16, one wave/node ----------------
__global__ __launch_bounds__(256) void k_degcast(const float* __restrict__ x,
                                                 const int* __restrict__ cnt,
                                                 const int2* __restrict__ ell,
                                                 float* __restrict__ dinv,
                                                 unsigned* __restrict__ bhs) {
  int node = blockIdx.x * 4 + (threadIdx.x >> 6);
  if (node >= N) return;
  int lane = threadIdx.x & 63;

  int len = cnt[node];
  float sum = (lane < len) ? __int_as_float(ell[(size_t)node * CAP + lane].y) : 0.f;
#pragma unroll
  for (int off = 1; off < 64; off <<= 1) sum += __shfl_xor(sum, off, 64);

  float dv = 1.0f / sqrtf(1.0f + sum);
  if (lane == 0) dinv[node] = dv;

  float2 v = ((const float2*)x)[(size_t)node * 64 + lane];
  bhs[(size_t)node * 64 + lane] = pack_bf16(v.x * dv, v.y * dv);
}

// ---------------- aggregation core (bf16 scaled gather, fp32 accumulate) ----------------
__device__ __forceinline__ float2 agg_core(const unsigned* __restrict__ bp,
                                           const int2* __restrict__ ell,
                                           int node, int len, float s) {
  unsigned hb = bp[(size_t)node * 64];
  float ax = blo(hb), ay = bhi(hb);

  const int2* row = ell + (size_t)node * CAP;
  int e = 0;
  for (; e + 8 <= len; e += 8) {
    int4 p0 = *(const int4*)(row + e + 0);
    int4 p1 = *(const int4*)(row + e + 2);
    int4 p2 = *(const int4*)(row + e + 4);
    int4 p3 = *(const int4*)(row + e + 6);
    unsigned b0 = bp[(size_t)p0.x * 64];
    unsigned b1 = bp[(size_t)p0.z * 64];
    unsigned b2 = bp[(size_t)p1.x * 64];
    unsigned b3 = bp[(size_t)p1.z * 64];
    unsigned b4 = bp[(size_t)p2.x * 64];
    unsigned b5 = bp[(size_t)p2.z * 64];
    unsigned b6 = bp[(size_t)p3.x * 64];
    unsigned b7 = bp[(size_t)p3.z * 64];
    float w0 = __int_as_float(p0.y), w1 = __int_as_float(p0.w);
    float w2 = __int_as_float(p1.y), w3 = __int_as_float(p1.w);
    float w4 = __int_as_float(p2.y), w5 = __int_as_float(p2.w);
    float w6 = __int_as_float(p3.y), w7 = __int_as_float(p3.w);
    ax = fmaf(blo(b0), w0, ax); ay = fmaf(bhi(b0), w0, ay);
    ax = fmaf(blo(b1), w1, ax); ay = fmaf(bhi(b1), w1, ay);
    ax = fmaf(blo(b2), w2, ax); ay = fmaf(bhi(b2), w2, ay);
    ax = fmaf(blo(b3), w3, ax); ay = fmaf(bhi(b3), w3, ay);
    ax = fmaf(blo(b4), w4, ax); ay = fmaf(bhi(b4), w4, ay);
    ax = fmaf(blo(b5), w5, ax); ay = fmaf(bhi(b5), w5, ay);
    ax = fmaf(blo(b6), w6, ax); ay = fmaf(bhi(b6), w6, ay);
    ax = fmaf(blo(b7), w7, ax); ay = fmaf(bhi(b7), w7, ay);
  }
  for (; e + 2 <= len; e += 2) {
    int4 p0 = *(const int4*)(row + e);
    unsigned b0 = bp[(size_t)p0.x * 64];
    unsigned b1 = bp[(size_t)p0.z * 64];
    float w0 = __int_as_float(p0.y), w1 = __int_as_float(p0.w);
    ax = fmaf(blo(b0), w0, ax); ay = fmaf(bhi(b0), w0, ay);
    ax = fmaf(blo(b1), w1, ax); ay = fmaf(bhi(b1), w1, ay);
  }
  if (e < len) {
    int2 pe = row[e];
    float w = __int_as_float(pe.y);
    unsigned b = bp[(size_t)pe.x * 64];
    ax = fmaf(blo(b), w, ax); ay = fmaf(bhi(b), w, ay);
  }
  float2 r; r.x = ax * s; r.y = ay * s;
  return r;
}

// ---------------- fused layer: aggregate 64 nodes -> LDS -> MFMA -> bf16 out ----------------
// block = 1024 threads = 16 waves; wave aggregates 4 nodes; then 2 MFMA tiles/wave
__global__ __launch_bounds__(1024) void k_layer_fused(const unsigned* __restrict__ bhs,
                                                      const int* __restrict__ cnt,
                                                      const int2* __restrict__ ell,
                                                      const float* __restrict__ dinv,
                                                      const float* __restrict__ W,
                                                      const float* __restrict__ bias,
                                                      unsigned* __restrict__ outb) {
  __shared__ __align__(16) unsigned Al[64][68];   // 64 rows x 64 uints (+4 pad)
  __shared__ __align__(16) unsigned Wt[128][72];  // 128 cols x 64 uints (+8 pad)
  const int tid = threadIdx.x;
  const int row0 = blockIdx.x * 64;

  {  // stage W transposed+bf16: Wt[col][k2] = (W[2k2][col], W[2k2+1][col])
    int col = tid & 127, seg = tid >> 7;   // 8 segs x 8 words
#pragma unroll
    for (int m = 0; m < 8; ++m) {
      int k2 = seg * 8 + m;
      float w0 = W[(size_t)(2 * k2) * 128 + col];
      float w1 = W[(size_t)(2 * k2 + 1) * 128 + col];
      Wt[col][k2] = pack_bf16(w0, w1);
    }
  }

  const int w = tid >> 6, l = tid & 63;
#pragma unroll 1
  for (int i = 0; i < 4; ++i) {           // aggregate this wave's 4 nodes
    int r = 4 * w + i;
    int node = row0 + r;
    unsigned val = 0u;
    if (node < N) {
      float2 rr = agg_core(bhs + l, ell, node, cnt[node], dinv[node]);
      val = pack_bf16(rr.x, rr.y);
    }
    Al[r][l] = val;
  }
  __syncthreads();

  // MFMA: 32 tiles (4 row-tiles x 8 col-tiles), 2 per wave
  const int c = l & 15, q = l >> 4;
#pragma unroll
  for (int t2 = 0; t2 < 2; ++t2) {
    int t = 2 * w + t2;
    int rt = t >> 3, ct = t & 7;
    f32x4 acc = {};
#pragma unroll
    for (int ks = 0; ks < 4; ++ks) {
      bf16x8 af = *(const bf16x8*)&Al[rt * 16 + c][ks * 16 + 4 * q];
      bf16x8 bf = *(const bf16x8*)&Wt[ct * 16 + c][ks * 16 + 4 * q];
      acc = __builtin_amdgcn_mfma_f32_16x16x32_bf16(af, bf, acc, 0, 0, 0);
    }
    int col = ct * 16 + c;
    float bb = bias[col];
#pragma unroll
    for (int j = 0; j < 4; ++j) {
      int row = row0 + rt * 16 + 4 * q + j;
      float v = 0.f;
      if (row < N) v = fmaxf(acc[j] + bb, 0.f) * dinv[row];
      float o = __shfl_xor(v, 1);
      if (((c & 1) == 0) && row < N)
        outb[(size_t)row * 64 + (col >> 1)] = pack_bf16(v, o);
    }
  }
}

// ---------------- fused head: aggregate -> LDS -> dual MFMA -> fp32 mu/std ----------------
__global__ __launch_bounds__(1024) void k_head_fused(const unsigned* __restrict__ bhs,
                                                     const int* __restrict__ cnt,
                                                     const int2* __restrict__ ell,
                                                     const float* __restrict__ dinv,
                                                     const float* __restrict__ Wmu,
                                                     const float* __restrict__ Wstd,
                                                     const float* __restrict__ bmu,
                                                     const float* __restrict__ bstd,
                                                     float* __restrict__ out) {
  __shared__ __align__(16) unsigned Al[64][68];
  __shared__ __align__(16) unsigned Wt[128][72];
  const int tid = threadIdx.x;
  const int row0 = blockIdx.x * 64;

  {  // Wt = [Wmu | Wstd] transposed+bf16
    int col = tid & 127, seg = tid >> 7;
    const float* base = (col < DO) ? Wmu : Wstd;
    int cc = (col < DO) ? col : (col - DO);
#pragma unroll
    for (int m = 0; m < 8; ++m) {
      int k2 = seg * 8 + m;
      float w0 = base[(size_t)(2 * k2) * DO + cc];
      float w1 = base[(size_t)(2 * k2 + 1) * DO + cc];
      Wt[col][k2] = pack_bf16(w0, w1);
    }
  }

  const int w = tid >> 6, l = tid & 63;
#pragma unroll 1
  for (int i = 0; i < 4; ++i) {
    int r = 4 * w + i;
    int node = row0 + r;
    unsigned val = 0u;
    if (node < N) {
      float2 rr = agg_core(bhs + l, ell, node, cnt[node], dinv[node]);
      val = pack_bf16(rr.x, rr.y);
    }
    Al[r][l] = val;
  }
  __syncthreads();

  const int c = l & 15, q = l >> 4;
#pragma unroll
  for (int t2 = 0; t2 < 2; ++t2) {
    int t = 2 * w + t2;
    int rt = t >> 3, ct = t & 7;
    f32x4 acc = {};
#pragma unroll
    for (int ks = 0; ks < 4; ++ks) {
      bf16x8 af = *(const bf16x8*)&Al[rt * 16 + c][ks * 16 + 4 * q];
      bf16x8 bf = *(const bf16x8*)&Wt[ct * 16 + c][ks * 16 + 4 * q];
      acc = __builtin_amdgcn_mfma_f32_16x16x32_bf16(af, bf, acc, 0, 0, 0);
    }
    int col = ct * 16 + c;
    const bool is_mu = (col < DO);
    float bb = is_mu ? bmu[col] : bstd[col - DO];
    float* base = is_mu ? out : (out + (size_t)N * DO);
    int cc = is_mu ? col : (col - DO);
#pragma unroll
    for (int j = 0; j < 4; ++j) {
      int row = row0 + rt * 16 + 4 * q + j;
      if (row < N) base[(size_t)row * DO + cc] = acc[j] + bb;
    }
  }
}

// ---------------- launcher ----------------

static inline char* align256(char* p) {
  return (char*)(((uintptr_t)p + 255) & ~(uintptr_t)255);
}

extern "C" void kernel_launch(void* const* d_in, const int* in_sizes, int n_in,
                              void* d_out, int out_size, void* d_ws, size_t ws_size,
                              hipStream_t stream) {
  const float* x    = (const float*)d_in[0];
  const int*   ei   = (const int*)d_in[1];     // [2, E] int32
  const float* ew   = (const float*)d_in[2];
  const float* W1   = (const float*)d_in[3];
  const float* b1   = (const float*)d_in[4];
  const float* W2   = (const float*)d_in[5];
  const float* b2   = (const float*)d_in[6];
  const float* Wmu  = (const float*)d_in[7];
  const float* bmu  = (const float*)d_in[8];
  const float* Wstd = (const float*)d_in[9];
  const float* bstd = (const float*)d_in[10];
  float* out = (float*)d_out;

  const int* srcI = ei;
  const int* dstI = ei + E;

  char* p = (char*)d_ws;
  float*    dinv = (float*)p;     p = align256(p + (size_t)N * 4);
  int*      cnt  = (int*)p;       p = align256(p + (size_t)N * 4);
  int2*     ell  = (int2*)p;      p = align256(p + (size_t)N * CAP * 8);  // 25.6 MB
  unsigned* bhs  = (unsigned*)p;  p = align256(p + (size_t)N * 64 * 4);   // 12.8 MB
  unsigned* bh2  = (unsigned*)p;  p = align256(p + (size_t)N * 64 * 4);   // 12.8 MB

  dim3 blk(256);
  const int gN    = (N + 255) / 256;
  const int gE    = (E + 255) / 256;
  const int gAgg  = (N + 3) / 4;
  const int gFuse = (N + 63) / 64;   // 782

  // graph precompute: zero -> single-pass ELL build -> deg/dinv/cast
  k_zero<<<gN, blk, 0, stream>>>(cnt);
  k_build_ell<<<gE, blk, 0, stream>>>(srcI, dstI, ew, cnt, ell);
  k_degcast<<<gAgg, blk, 0, stream>>>(x, cnt, ell, dinv, bhs);

  // layer 1: bhs -> bh2
  k_layer_fused<<<gFuse, dim3(1024), 0, stream>>>(bhs, cnt, ell, dinv, W1, b1, bh2);
  // layer 2: bh2 -> bhs
  k_layer_fused<<<gFuse, dim3(1024), 0, stream>>>(bh2, cnt, ell, dinv, W2, b2, bhs);
  // head: bhs -> out (mu, std)
  k_head_fused<<<gFuse, dim3(1024), 0, stream>>>(bhs, cnt, ell, dinv, Wmu, Wstd, bmu, bstd, out);
}

// Round 15
// 193.111 us; speedup vs baseline: 1.5279x; 1.0400x over previous
//
#include <hip/hip_runtime.h>
#include <hip/hip_fp16.h>
#include <math.h>

static constexpr int N = 50000;    // < 65536 -> src fits u16
static constexpr int E = 800000;
static constexpr int D = 128;      // D_IN = D_HID
static constexpr int DO = 64;      // D_OUT
static constexpr int CAP = 64;     // ELL row capacity (Poisson(16); P(deg>64) ~ 1e-26)

// ---- bf16 helpers ----
__device__ __forceinline__ unsigned pack_bf16(float a, float b) {
  unsigned ua = __float_as_uint(a), ub = __float_as_uint(b);
  ua = (ua + 0x7FFFu + ((ua >> 16) & 1u)) >> 16;
  ub = (ub + 0x7FFFu + ((ub >> 16) & 1u)) >> 16;
  return ua | (ub << 16);
}
__device__ __forceinline__ float blo(unsigned u) { return __uint_as_float(u << 16); }
__device__ __forceinline__ float bhi(unsigned u) { return __uint_as_float(u & 0xFFFF0000u); }

// ---- ELL entry: low16 = src (u16), high16 = fp16 bits of raw ew ----
__device__ __forceinline__ unsigned ell_pack(int s, float w) {
  return (unsigned)s | ((unsigned)__half_as_ushort(__float2half(w)) << 16);
}
__device__ __forceinline__ float ell_w(unsigned p) {
  return __half2float(__ushort_as_half((unsigned short)(p >> 16)));
}

typedef __attribute__((ext_vector_type(8))) short bf16x8;
typedef __attribute__((ext_vector_type(4))) float f32x4;

// ---------------- zero per-dst counters ----------------
__global__ __launch_bounds__(256) void k_zero(int* __restrict__ cnt) {
  int i = blockIdx.x * 256 + threadIdx.x;
  if (i < N) cnt[i] = 0;
}

// ---------------- single-pass ELL build, 4-edge ILP per thread ----------------
__global__ __launch_bounds__(256) void k_build_ell(const int* __restrict__ src,
                                                   const int* __restrict__ dst,
                                                   const float* __restrict__ ew,
                                                   int* __restrict__ cnt,
                                                   unsigned* __restrict__ ell) {
  int e0 = blockIdx.x * 1024 + threadIdx.x;
  int d[4], s[4];
  float w[4];
  bool ok[4];
#pragma unroll
  for (int i = 0; i < 4; ++i) {
    int e = e0 + i * 256;
    ok[i] = (e < E);
    if (ok[i]) { d[i] = dst[e]; s[i] = src[e]; w[i] = ew[e]; }
  }
  int pos[4];
#pragma unroll
  for (int i = 0; i < 4; ++i)   // 4 independent returning atomics in flight
    if (ok[i])
      pos[i] = __hip_atomic_fetch_add(&cnt[d[i]], 1, __ATOMIC_RELAXED, __HIP_MEMORY_SCOPE_AGENT);
#pragma unroll
  for (int i = 0; i < 4; ++i)
    if (ok[i] && pos[i] < CAP)   // statistically unreachable; guards memory safety
      ell[(size_t)d[i] * CAP + pos[i]] = ell_pack(s[i], w[i]);
}

// ---------------- deg -> dinv -> cast x to scaled bf16, one wave/node ----------------
__global__ __launch_bounds__(256) void k_degcast(const float* __restrict__ x,
                                                 const int* __restrict__ cnt,
                                                 const unsigned* __restrict__ ell,
                                                 float* __restrict__ dinv,
                                                 unsigned* __restrict__ bhs) {
  int node = blockIdx.x * 4 + (threadIdx.x >> 6);
  if (node >= N) return;
  int lane = threadIdx.x & 63;

  int len = cnt[node];
  float sum = (lane < len) ? ell_w(ell[(size_t)node * CAP + lane]) : 0.f;
#pragma unroll
  for (int off = 1; off < 64; off <<= 1) sum += __shfl_xor(sum, off, 64);

  float dv = 1.0f / sqrtf(1.0f + sum);
  if (lane == 0) dinv[node] = dv;

  float2 v = ((const float2*)x)[(size_t)node * 64 + lane];
  bhs[(size_t)node * 64 + lane] = pack_bf16(v.x * dv, v.y * dv);
}

// ---------------- aggregation core (bf16 scaled gather, fp32 accumulate) ----------------
// returns dinv[node] * ( bhs[node] + sum_e ew_e * bhs[src_e] )  per lane (2 dims)
__device__ __forceinline__ float2 agg_core(const unsigned* __restrict__ bp,
                                           const unsigned* __restrict__ ell,
                                           int node, int len, float s) {
  unsigned hb = bp[(size_t)node * 64];
  float ax = blo(hb), ay = bhi(hb);

  const unsigned* row = ell + (size_t)node * CAP;
  int e = 0;
  for (; e + 8 <= len; e += 8) {
    uint4 p0 = *(const uint4*)(row + e);
    uint4 p1 = *(const uint4*)(row + e + 4);
    unsigned b0 = bp[(size_t)(p0.x & 0xFFFFu) * 64];
    unsigned b1 = bp[(size_t)(p0.y & 0xFFFFu) * 64];
    unsigned b2 = bp[(size_t)(p0.z & 0xFFFFu) * 64];
    unsigned b3 = bp[(size_t)(p0.w & 0xFFFFu) * 64];
    unsigned b4 = bp[(size_t)(p1.x & 0xFFFFu) * 64];
    unsigned b5 = bp[(size_t)(p1.y & 0xFFFFu) * 64];
    unsigned b6 = bp[(size_t)(p1.z & 0xFFFFu) * 64];
    unsigned b7 = bp[(size_t)(p1.w & 0xFFFFu) * 64];
    float w0 = ell_w(p0.x), w1 = ell_w(p0.y), w2 = ell_w(p0.z), w3 = ell_w(p0.w);
    float w4 = ell_w(p1.x), w5 = ell_w(p1.y), w6 = ell_w(p1.z), w7 = ell_w(p1.w);
    ax = fmaf(blo(b0), w0, ax); ay = fmaf(bhi(b0), w0, ay);
    ax = fmaf(blo(b1), w1, ax); ay = fmaf(bhi(b1), w1, ay);
    ax = fmaf(blo(b2), w2, ax); ay = fmaf(bhi(b2), w2, ay);
    ax = fmaf(blo(b3), w3, ax); ay = fmaf(bhi(b3), w3, ay);
    ax = fmaf(blo(b4), w4, ax); ay = fmaf(bhi(b4), w4, ay);
    ax = fmaf(blo(b5), w5, ax); ay = fmaf(bhi(b5), w5, ay);
    ax = fmaf(blo(b6), w6, ax); ay = fmaf(bhi(b6), w6, ay);
    ax = fmaf(blo(b7), w7, ax); ay = fmaf(bhi(b7), w7, ay);
  }
  if (e + 4 <= len) {
    uint4 p0 = *(const uint4*)(row + e);
    unsigned b0 = bp[(size_t)(p0.x & 0xFFFFu) * 64];
    unsigned b1 = bp[(size_t)(p0.y & 0xFFFFu) * 64];
    unsigned b2 = bp[(size_t)(p0.z & 0xFFFFu) * 64];
    unsigned b3 = bp[(size_t)(p0.w & 0xFFFFu) * 64];
    float w0 = ell_w(p0.x), w1 = ell_w(p0.y), w2 = ell_w(p0.z), w3 = ell_w(p0.w);
    ax = fmaf(blo(b0), w0, ax); ay = fmaf(bhi(b0), w0, ay);
    ax = fmaf(blo(b1), w1, ax); ay = fmaf(bhi(b1), w1, ay);
    ax = fmaf(blo(b2), w2, ax); ay = fmaf(bhi(b2), w2, ay);
    ax = fmaf(blo(b3), w3, ax); ay = fmaf(bhi(b3), w3, ay);
    e += 4;
  }
  for (; e < len; ++e) {
    unsigned pe = row[e];
    float w = ell_w(pe);
    unsigned b = bp[(size_t)(pe & 0xFFFFu) * 64];
    ax = fmaf(blo(b), w, ax); ay = fmaf(bhi(b), w, ay);
  }
  float2 r; r.x = ax * s; r.y = ay * s;
  return r;
}

// ---------------- fused layer: aggregate 64 nodes -> LDS -> MFMA -> bf16 out ----------------
// block = 1024 threads = 16 waves; wave aggregates 4 nodes; then 2 MFMA tiles/wave
__global__ __launch_bounds__(1024) void k_layer_fused(const unsigned* __restrict__ bhs,
                                                      const int* __restrict__ cnt,
                                                      const unsigned* __restrict__ ell,
                                                      const float* __restrict__ dinv,
                                                      const float* __restrict__ W,
                                                      const float* __restrict__ bias,
                                                      unsigned* __restrict__ outb) {
  __shared__ __align__(16) unsigned Al[64][68];   // 64 rows x 64 uints (+4 pad)
  __shared__ __align__(16) unsigned Wt[128][72];  // 128 cols x 64 uints (+8 pad)
  const int tid = threadIdx.x;
  const int row0 = blockIdx.x * 64;

  {  // stage W transposed+bf16: Wt[col][k2] = (W[2k2][col], W[2k2+1][col])
    int col = tid & 127, seg = tid >> 7;   // 8 segs x 8 words
#pragma unroll
    for (int m = 0; m < 8; ++m) {
      int k2 = seg * 8 + m;
      float w0 = W[(size_t)(2 * k2) * 128 + col];
      float w1 = W[(size_t)(2 * k2 + 1) * 128 + col];
      Wt[col][k2] = pack_bf16(w0, w1);
    }
  }

  const int w = tid >> 6, l = tid & 63;
#pragma unroll 1
  for (int i = 0; i < 4; ++i) {           // aggregate this wave's 4 nodes
    int r = 4 * w + i;
    int node = row0 + r;
    unsigned val = 0u;
    if (node < N) {
      float2 rr = agg_core(bhs + l, ell, node, cnt[node], dinv[node]);
      val = pack_bf16(rr.x, rr.y);
    }
    Al[r][l] = val;
  }
  __syncthreads();

  // MFMA: 32 tiles (4 row-tiles x 8 col-tiles), 2 per wave
  const int c = l & 15, q = l >> 4;
#pragma unroll
  for (int t2 = 0; t2 < 2; ++t2) {
    int t = 2 * w + t2;
    int rt = t >> 3, ct = t & 7;
    f32x4 acc = {};
#pragma unroll
    for (int ks = 0; ks < 4; ++ks) {
      bf16x8 af = *(const bf16x8*)&Al[rt * 16 + c][ks * 16 + 4 * q];
      bf16x8 bf = *(const bf16x8*)&Wt[ct * 16 + c][ks * 16 + 4 * q];
      acc = __builtin_amdgcn_mfma_f32_16x16x32_bf16(af, bf, acc, 0, 0, 0);
    }
    int col = ct * 16 + c;
    float bb = bias[col];
#pragma unroll
    for (int j = 0; j < 4; ++j) {
      int row = row0 + rt * 16 + 4 * q + j;
      float v = 0.f;
      if (row < N) v = fmaxf(acc[j] + bb, 0.f) * dinv[row];
      float o = __shfl_xor(v, 1);
      if (((c & 1) == 0) && row < N)
        outb[(size_t)row * 64 + (col >> 1)] = pack_bf16(v, o);
    }
  }
}

// ---------------- fused head: aggregate -> LDS -> dual MFMA -> fp32 mu/std ----------------
__global__ __launch_bounds__(1024) void k_head_fused(const unsigned* __restrict__ bhs,
                                                     const int* __restrict__ cnt,
                                                     const unsigned* __restrict__ ell,
                                                     const float* __restrict__ dinv,
                                                     const float* __restrict__ Wmu,
                                                     const float* __restrict__ Wstd,
                                                     const float* __restrict__ bmu,
                                                     const float* __restrict__ bstd,
                                                     float* __restrict__ out) {
  __shared__ __align__(16) unsigned Al[64][68];
  __shared__ __align__(16) unsigned Wt[128][72];
  const int tid = threadIdx.x;
  const int row0 = blockIdx.x * 64;

  {  // Wt = [Wmu | Wstd] transposed+bf16
    int col = tid & 127, seg = tid >> 7;
    const float* base = (col < DO) ? Wmu : Wstd;
    int cc = (col < DO) ? col : (col - DO);
#pragma unroll
    for (int m = 0; m < 8; ++m) {
      int k2 = seg * 8 + m;
      float w0 = base[(size_t)(2 * k2) * DO + cc];
      float w1 = base[(size_t)(2 * k2 + 1) * DO + cc];
      Wt[col][k2] = pack_bf16(w0, w1);
    }
  }

  const int w = tid >> 6, l = tid & 63;
#pragma unroll 1
  for (int i = 0; i < 4; ++i) {
    int r = 4 * w + i;
    int node = row0 + r;
    unsigned val = 0u;
    if (node < N) {
      float2 rr = agg_core(bhs + l, ell, node, cnt[node], dinv[node]);
      val = pack_bf16(rr.x, rr.y);
    }
    Al[r][l] = val;
  }
  __syncthreads();

  const int c = l & 15, q = l >> 4;
#pragma unroll
  for (int t2 = 0; t2 < 2; ++t2) {
    int t = 2 * w + t2;
    int rt = t >> 3, ct = t & 7;
    f32x4 acc = {};
#pragma unroll
    for (int ks = 0; ks < 4; ++ks) {
      bf16x8 af = *(const bf16x8*)&Al[rt * 16 + c][ks * 16 + 4 * q];
      bf16x8 bf = *(const bf16x8*)&Wt[ct * 16 + c][ks * 16 + 4 * q];
      acc = __builtin_amdgcn_mfma_f32_16x16x32_bf16(af, bf, acc, 0, 0, 0);
    }
    int col = ct * 16 + c;
    const bool is_mu = (col < DO);
    float bb = is_mu ? bmu[col] : bstd[col - DO];
    float* base = is_mu ? out : (out + (size_t)N * DO);
    int cc = is_mu ? col : (col - DO);
#pragma unroll
    for (int j = 0; j < 4; ++j) {
      int row = row0 + rt * 16 + 4 * q + j;
      if (row < N) base[(size_t)row * DO + cc] = acc[j] + bb;
    }
  }
}

// ---------------- launcher ----------------

static inline char* align256(char* p) {
  return (char*)(((uintptr_t)p + 255) & ~(uintptr_t)255);
}

extern "C" void kernel_launch(void* const* d_in, const int* in_sizes, int n_in,
                              void* d_out, int out_size, void* d_ws, size_t ws_size,
                              hipStream_t stream) {
  const float* x    = (const float*)d_in[0];
  const int*   ei   = (const int*)d_in[1];     // [2, E] int32
  const float* ew   = (const float*)d_in[2];
  const float* W1   = (const float*)d_in[3];
  const float* b1   = (const float*)d_in[4];
  const float* W2   = (const float*)d_in[5];
  const float* b2   = (const float*)d_in[6];
  const float* Wmu  = (const float*)d_in[7];
  const float* bmu  = (const float*)d_in[8];
  const float* Wstd = (const float*)d_in[9];
  const float* bstd = (const float*)d_in[10];
  float* out = (float*)d_out;

  const int* srcI = ei;
  const int* dstI = ei + E;

  char* p = (char*)d_ws;
  float*    dinv = (float*)p;     p = align256(p + (size_t)N * 4);
  int*      cnt  = (int*)p;       p = align256(p + (size_t)N * 4);
  unsigned* ell  = (unsigned*)p;  p = align256(p + (size_t)N * CAP * 4);  // 12.8 MB
  unsigned* bhs  = (unsigned*)p;  p = align256(p + (size_t)N * 64 * 4);   // 12.8 MB
  unsigned* bh2  = (unsigned*)p;  p = align256(p + (size_t)N * 64 * 4);   // 12.8 MB

  dim3 blk(256);
  const int gN     = (N + 255) / 256;
  const int gBuild = (E + 1023) / 1024;   // 4 edges/thread
  const int gAgg   = (N + 3) / 4;
  const int gFuse  = (N + 63) / 64;       // 782

  // graph precompute: zero -> single-pass ELL build (4x ILP) -> deg/dinv/cast
  k_zero<<<gN, blk, 0, stream>>>(cnt);
  k_build_ell<<<gBuild, blk, 0, stream>>>(srcI, dstI, ew, cnt, ell);
  k_degcast<<<gAgg, blk, 0, stream>>>(x, cnt, ell, dinv, bhs);

  // layer 1: bhs -> bh2
  k_layer_fused<<<gFuse, dim3(1024), 0, stream>>>(bhs, cnt, ell, dinv, W1, b1, bh2);
  // layer 2: bh2 -> bhs
  k_layer_fused<<<gFuse, dim3(1024), 0, stream>>>(bh2, cnt, ell, dinv, W2, b2, bhs);
  // head: bhs -> out (mu, std)
  k_head_fused<<<gFuse, dim3(1024), 0, stream>>>(bhs, cnt, ell, dinv, Wmu, Wstd, bmu, bstd, out);
}